// Round 6
// baseline (2984.600 us; speedup 1.0000x reference)
//
#include <hip/hip_runtime.h>
#include <cstdint>

#define NPOS 32768
#define IND  512
#define HID  512
#define OUTF 256

// divtab[k] bit (t-1) set iff t % k == 0, t in 1..16. divtab[0] unused (no spike).
__constant__ unsigned divtab[17] = {
    0x0000u,
    0xFFFFu,  // k=1
    0xAAAAu,  // k=2
    0x4924u,  // k=3  (t=3,6,9,12,15)
    0x8888u,  // k=4
    0x4210u,  // k=5  (t=5,10,15)
    0x0820u,  // k=6  (t=6,12)
    0x2040u,  // k=7  (t=7,14)
    0x8080u,  // k=8  (t=8,16)
    0x0100u, 0x0200u, 0x0400u, 0x0800u,   // k=9..12
    0x1000u, 0x2000u, 0x4000u, 0x8000u    // k=13..16
};

// ---------------------------------------------------------------------------
// K0: transpose W2 [256][512] -> w2t [512][256] (pure copy; values exact)
// ---------------------------------------------------------------------------
__global__ __launch_bounds__(256) void k_transpose(const float* __restrict__ W2,
                                                   float* __restrict__ w2t) {
  __shared__ float tile[32][33];
  int x = threadIdx.x & 31, y = threadIdx.x >> 5;  // 32 x 8
  int hb = blockIdx.x * 32, ob = blockIdx.y * 32;
#pragma unroll
  for (int dy = 0; dy < 32; dy += 8)
    tile[y + dy][x] = W2[(size_t)(ob + y + dy) * HID + hb + x];
  __syncthreads();
#pragma unroll
  for (int dy = 0; dy < 32; dy += 8)
    w2t[(size_t)(hb + y + dy) * OUTF + ob + x] = tile[x][y + dy];
}

// ---------------------------------------------------------------------------
// K1: fc1 GEMM, fp32, BIT-EXACT strict-sequential model of the np reference
// (single accumulator, ascending i, separate mul+add, no FMA), fused
// LIF-period epilogue -> kmap[pos][h] = first crossing step k (0 = never).
// UNCHANGED from the passing round-5 kernel.
// ---------------------------------------------------------------------------
__global__ __launch_bounds__(256) void k_fc1_kmap(const float* __restrict__ X,
                                                  const float* __restrict__ W1,
                                                  const float* __restrict__ b1,
                                                  unsigned char* __restrict__ kmap) {
  __shared__ float As[8][128];
  __shared__ float Bs[8][128];
  const int row0 = blockIdx.x * 128;   // position tile (32768/128 = 256)
  const int col0 = blockIdx.y * 128;   // hidden tile   (512/128 = 4)
  const int t = threadIdx.x;
  const int tm0 = (t & 15) * 8;
  const int tn0 = (t >> 4) * 8;

  float c[8][8];
#pragma unroll
  for (int i = 0; i < 8; ++i)
#pragma unroll
    for (int j = 0; j < 8; ++j) c[i][j] = 0.0f;

  const int sm = t >> 1;          // 0..127
  const int sk = (t & 1) * 4;     // 0 or 4

  for (int kt = 0; kt < IND; kt += 8) {
    float4 va = *(const float4*)(X + (size_t)(row0 + sm) * IND + kt + sk);
    float4 vb = *(const float4*)(W1 + (size_t)(col0 + sm) * IND + kt + sk);
    __syncthreads();   // protect previous iteration's LDS reads
    As[sk + 0][sm] = va.x; As[sk + 1][sm] = va.y;
    As[sk + 2][sm] = va.z; As[sk + 3][sm] = va.w;
    Bs[sk + 0][sm] = vb.x; Bs[sk + 1][sm] = vb.y;
    Bs[sk + 2][sm] = vb.z; Bs[sk + 3][sm] = vb.w;
    __syncthreads();
#pragma unroll
    for (int kk = 0; kk < 8; ++kk) {   // global i = kt + kk, strictly ascending
      float4 a0 = *(const float4*)&As[kk][tm0];
      float4 a1 = *(const float4*)&As[kk][tm0 + 4];
      float4 b0 = *(const float4*)&Bs[kk][tn0];
      float4 b1_ = *(const float4*)&Bs[kk][tn0 + 4];
      float a[8] = {a0.x, a0.y, a0.z, a0.w, a1.x, a1.y, a1.z, a1.w};
      float b[8] = {b0.x, b0.y, b0.z, b0.w, b1_.x, b1_.y, b1_.z, b1_.w};
#pragma unroll
      for (int i = 0; i < 8; ++i)
#pragma unroll
        for (int j = 0; j < 8; ++j)
          c[i][j] = __fadd_rn(c[i][j], __fmul_rn(a[i], b[j]));  // no contraction
    }
  }

  float4 b1a = *(const float4*)(b1 + col0 + tn0);
  float4 b1b = *(const float4*)(b1 + col0 + tn0 + 4);
  float b1v[8] = {b1a.x, b1a.y, b1a.z, b1a.w, b1b.x, b1b.y, b1b.z, b1b.w};

#pragma unroll
  for (int i = 0; i < 8; ++i) {
    unsigned long long pk = 0;
#pragma unroll
    for (int j = 0; j < 8; ++j) {
      float pre = __fadd_rn(c[i][j], b1v[j]);
      float m = 0.0f;
      int kv = 0;
#pragma unroll
      for (int tt = 1; tt <= 16; ++tt) {
        m = __fadd_rn(m, pre);
        if (m > 0.5f && kv == 0) kv = tt;
      }
      pk |= (unsigned long long)(unsigned int)kv << (8 * j);
    }
    *(unsigned long long*)(kmap + (size_t)(row0 + tm0 + i) * HID + col0 + tn0) = pk;
  }
}

// ---------------------------------------------------------------------------
// K2: exact-order fc2 + mem2 sim — straight-line masked-FMA form.
// Per spiking h (k wave-uniform, scalar-decoded): acc_t = fmaf(m_t, w, acc_t)
// with m_t = bit (t-1) of divtab[k] as 1.0f/0.0f. fma(1*w+acc) rounds once ==
// fadd(acc,w); fma(0*w+acc) == acc (+-0 adds are value-exact) -> the per-t
// add sequences are IDENTICAL to the round-5 passing kernel (absmax 0.0),
// but codegen is branch-free vector code + SALU selects (no switch).
// Block = 256 threads = one position; thread owns o = tid.
// ---------------------------------------------------------------------------
__global__ __launch_bounds__(256) void k_snn_fc2(const unsigned char* __restrict__ kmap,
                                                 const float* __restrict__ w2t,
                                                 const float* __restrict__ b2,
                                                 float* __restrict__ out) {
  const int tid = threadIdx.x;            // o = tid
  const size_t pos = blockIdx.x;

  float a1 = 0.f, a2 = 0.f, a3 = 0.f, a4 = 0.f, a5 = 0.f, a6 = 0.f,
        a7 = 0.f, a8 = 0.f, a9 = 0.f, a10 = 0.f, a11 = 0.f, a12 = 0.f,
        a13 = 0.f, a14 = 0.f, a15 = 0.f, a16 = 0.f;

  const uint4* kp = (const uint4*)(kmap + pos * HID);

#define DO_H(HB, KB)                                                      \
  do {                                                                    \
    unsigned kk_ = (KB);                                                  \
    if (kk_ != 0u) {                                                      \
      unsigned bits = divtab[kk_];   /* scalar load, k uniform */         \
      float w = w2t[(size_t)(HB) * OUTF + tid];                           \
      a1  = fmaf((bits & 0x0001u) ? 1.0f : 0.0f, w, a1);                  \
      a2  = fmaf((bits & 0x0002u) ? 1.0f : 0.0f, w, a2);                  \
      a3  = fmaf((bits & 0x0004u) ? 1.0f : 0.0f, w, a3);                  \
      a4  = fmaf((bits & 0x0008u) ? 1.0f : 0.0f, w, a4);                  \
      a5  = fmaf((bits & 0x0010u) ? 1.0f : 0.0f, w, a5);                  \
      a6  = fmaf((bits & 0x0020u) ? 1.0f : 0.0f, w, a6);                  \
      a7  = fmaf((bits & 0x0040u) ? 1.0f : 0.0f, w, a7);                  \
      a8  = fmaf((bits & 0x0080u) ? 1.0f : 0.0f, w, a8);                  \
      a9  = fmaf((bits & 0x0100u) ? 1.0f : 0.0f, w, a9);                  \
      a10 = fmaf((bits & 0x0200u) ? 1.0f : 0.0f, w, a10);                 \
      a11 = fmaf((bits & 0x0400u) ? 1.0f : 0.0f, w, a11);                 \
      a12 = fmaf((bits & 0x0800u) ? 1.0f : 0.0f, w, a12);                 \
      a13 = fmaf((bits & 0x1000u) ? 1.0f : 0.0f, w, a13);                 \
      a14 = fmaf((bits & 0x2000u) ? 1.0f : 0.0f, w, a14);                 \
      a15 = fmaf((bits & 0x4000u) ? 1.0f : 0.0f, w, a15);                 \
      a16 = fmaf((bits & 0x8000u) ? 1.0f : 0.0f, w, a16);                 \
    }                                                                     \
  } while (0)

  for (int it = 0; it < 32; ++it) {       // h ascending in groups of 16
    uint4 kw = kp[it];                    // wave-uniform address
    int hb = it * 16;
    {
      unsigned uw = __builtin_amdgcn_readfirstlane(kw.x);
      DO_H(hb + 0, uw & 255u);        DO_H(hb + 1, (uw >> 8) & 255u);
      DO_H(hb + 2, (uw >> 16) & 255u); DO_H(hb + 3, uw >> 24);
    }
    {
      unsigned uw = __builtin_amdgcn_readfirstlane(kw.y);
      DO_H(hb + 4, uw & 255u);        DO_H(hb + 5, (uw >> 8) & 255u);
      DO_H(hb + 6, (uw >> 16) & 255u); DO_H(hb + 7, uw >> 24);
    }
    {
      unsigned uw = __builtin_amdgcn_readfirstlane(kw.z);
      DO_H(hb + 8, uw & 255u);        DO_H(hb + 9, (uw >> 8) & 255u);
      DO_H(hb + 10, (uw >> 16) & 255u); DO_H(hb + 11, uw >> 24);
    }
    {
      unsigned uw = __builtin_amdgcn_readfirstlane(kw.w);
      DO_H(hb + 12, uw & 255u);       DO_H(hb + 13, (uw >> 8) & 255u);
      DO_H(hb + 14, (uw >> 16) & 255u); DO_H(hb + 15, uw >> 24);
    }
  }
#undef DO_H

  // mem2 simulation, exact fp32: mem = (mem + c_t) + b2; spike; reset.
  float b2v = b2[tid];
  float mem = 0.0f, ss = 0.0f;
#define STEP(CT)                                            \
  do {                                                      \
    mem = __fadd_rn(__fadd_rn(mem, (CT)), b2v);             \
    if (mem > 0.5f) { ss += 1.0f; mem = 0.0f; }             \
  } while (0)
  STEP(a1);  STEP(a2);  STEP(a3);  STEP(a4);
  STEP(a5);  STEP(a6);  STEP(a7);  STEP(a8);
  STEP(a9);  STEP(a10); STEP(a11); STEP(a12);
  STEP(a13); STEP(a14); STEP(a15); STEP(a16);
#undef STEP
  out[pos * OUTF + tid] = ss * 0.0625f;
}

// ---------------------------------------------------------------------------
extern "C" void kernel_launch(void* const* d_in, const int* in_sizes, int n_in,
                              void* d_out, int out_size, void* d_ws, size_t ws_size,
                              hipStream_t stream) {
  const float* X  = (const float*)d_in[0];   // [16,2048,512]
  const float* W1 = (const float*)d_in[1];   // [512,512]
  const float* b1 = (const float*)d_in[2];   // [512]
  const float* W2 = (const float*)d_in[3];   // [256,512]
  const float* b2 = (const float*)d_in[4];   // [256]
  float* out = (float*)d_out;                // [32768,256]

  float* w2t = (float*)d_ws;                                           // 512 KB
  unsigned char* kmap = (unsigned char*)d_ws + (size_t)HID * OUTF * 4; // 16 MB

  k_transpose<<<dim3(16, 8), 256, 0, stream>>>(W2, w2t);
  k_fc1_kmap<<<dim3(256, 4), 256, 0, stream>>>(X, W1, b1, kmap);
  k_snn_fc2<<<NPOS, 256, 0, stream>>>(kmap, w2t, b2, out);
}

// Round 7
// 1461.092 us; speedup vs baseline: 2.0427x; 2.0427x over previous
//
#include <hip/hip_runtime.h>
#include <cstdint>

#define NPOS 32768
#define IND  512
#define HID  512
#define OUTF 256

typedef float v2f __attribute__((ext_vector_type(2)));

// ---------------------------------------------------------------------------
// K0: transpose W2 [256][512] -> w2t [512][256] (pure copy; values exact)
// ---------------------------------------------------------------------------
__global__ __launch_bounds__(256) void k_transpose(const float* __restrict__ W2,
                                                   float* __restrict__ w2t) {
  __shared__ float tile[32][33];
  int x = threadIdx.x & 31, y = threadIdx.x >> 5;  // 32 x 8
  int hb = blockIdx.x * 32, ob = blockIdx.y * 32;
#pragma unroll
  for (int dy = 0; dy < 32; dy += 8)
    tile[y + dy][x] = W2[(size_t)(ob + y + dy) * HID + hb + x];
  __syncthreads();
#pragma unroll
  for (int dy = 0; dy < 32; dy += 8)
    w2t[(size_t)(hb + y + dy) * OUTF + ob + x] = tile[x][y + dy];
}

// ---------------------------------------------------------------------------
// K1: fc1 GEMM, fp32, BIT-EXACT strict-sequential model of the np reference
// (single accumulator, ascending i, separate mul+add, no FMA), fused
// LIF-period epilogue -> kmap[pos][h] = first crossing step k (0 = never).
// UNCHANGED from the passing round-4/5 kernel.
// ---------------------------------------------------------------------------
__global__ __launch_bounds__(256) void k_fc1_kmap(const float* __restrict__ X,
                                                  const float* __restrict__ W1,
                                                  const float* __restrict__ b1,
                                                  unsigned char* __restrict__ kmap) {
  __shared__ float As[8][128];
  __shared__ float Bs[8][128];
  const int row0 = blockIdx.x * 128;   // position tile (32768/128 = 256)
  const int col0 = blockIdx.y * 128;   // hidden tile   (512/128 = 4)
  const int t = threadIdx.x;
  const int tm0 = (t & 15) * 8;
  const int tn0 = (t >> 4) * 8;

  float c[8][8];
#pragma unroll
  for (int i = 0; i < 8; ++i)
#pragma unroll
    for (int j = 0; j < 8; ++j) c[i][j] = 0.0f;

  const int sm = t >> 1;          // 0..127
  const int sk = (t & 1) * 4;     // 0 or 4

  for (int kt = 0; kt < IND; kt += 8) {
    float4 va = *(const float4*)(X + (size_t)(row0 + sm) * IND + kt + sk);
    float4 vb = *(const float4*)(W1 + (size_t)(col0 + sm) * IND + kt + sk);
    __syncthreads();   // protect previous iteration's LDS reads
    As[sk + 0][sm] = va.x; As[sk + 1][sm] = va.y;
    As[sk + 2][sm] = va.z; As[sk + 3][sm] = va.w;
    Bs[sk + 0][sm] = vb.x; Bs[sk + 1][sm] = vb.y;
    Bs[sk + 2][sm] = vb.z; Bs[sk + 3][sm] = vb.w;
    __syncthreads();
#pragma unroll
    for (int kk = 0; kk < 8; ++kk) {   // global i = kt + kk, strictly ascending
      float4 a0 = *(const float4*)&As[kk][tm0];
      float4 a1 = *(const float4*)&As[kk][tm0 + 4];
      float4 b0 = *(const float4*)&Bs[kk][tn0];
      float4 b1_ = *(const float4*)&Bs[kk][tn0 + 4];
      float a[8] = {a0.x, a0.y, a0.z, a0.w, a1.x, a1.y, a1.z, a1.w};
      float b[8] = {b0.x, b0.y, b0.z, b0.w, b1_.x, b1_.y, b1_.z, b1_.w};
#pragma unroll
      for (int i = 0; i < 8; ++i)
#pragma unroll
        for (int j = 0; j < 8; ++j)
          c[i][j] = __fadd_rn(c[i][j], __fmul_rn(a[i], b[j]));  // no contraction
    }
  }

  float4 b1a = *(const float4*)(b1 + col0 + tn0);
  float4 b1b = *(const float4*)(b1 + col0 + tn0 + 4);
  float b1v[8] = {b1a.x, b1a.y, b1a.z, b1a.w, b1b.x, b1b.y, b1b.z, b1b.w};

#pragma unroll
  for (int i = 0; i < 8; ++i) {
    unsigned long long pk = 0;
#pragma unroll
    for (int j = 0; j < 8; ++j) {
      float pre = __fadd_rn(c[i][j], b1v[j]);
      float m = 0.0f;
      int kv = 0;
#pragma unroll
      for (int tt = 1; tt <= 16; ++tt) {
        m = __fadd_rn(m, pre);
        if (m > 0.5f && kv == 0) kv = tt;
      }
      pk |= (unsigned long long)(unsigned int)kv << (8 * j);
    }
    *(unsigned long long*)(kmap + (size_t)(row0 + tm0 + i) * HID + col0 + tn0) = pk;
  }
}

// ---------------------------------------------------------------------------
// K2: exact-order fc2 + mem2 sim — volatile v_pk_add_f32 switch.
// Thread i owns the output PAIR (o=2i, o=2i+1); the 16 per-t accumulators
// are float2; each useful add is one volatile "v_pk_add_f32" (two
// independent IEEE fp32 adds, identical rounding to v_add_f32 per half).
// volatile asm CANNOT be speculated -> the if(k)/switch(k) stay real
// wave-uniform branches (k is readfirstlane-uniform), so only the n_k
// useful adds execute (avg 4.8/h vs 16 for the if-converted versions).
// Per-o add sequences are IDENTICAL to the round-5 passing kernel.
// Block = 128 threads = one position (2 waves, no LDS, no syncs).
// ---------------------------------------------------------------------------
__global__ __launch_bounds__(128) void k_snn_fc2(const unsigned char* __restrict__ kmap,
                                                 const float* __restrict__ w2t,
                                                 const float* __restrict__ b2,
                                                 float* __restrict__ out) {
  const int tid = threadIdx.x;            // 0..127 -> o = 2*tid, 2*tid+1
  const size_t pos = blockIdx.x;

  v2f a1 = {0.f, 0.f}, a2 = a1, a3 = a1, a4 = a1, a5 = a1, a6 = a1,
      a7 = a1, a8 = a1, a9 = a1, a10 = a1, a11 = a1, a12 = a1,
      a13 = a1, a14 = a1, a15 = a1, a16 = a1;

  const uint4* kp = (const uint4*)(kmap + pos * HID);
  const v2f* w2p = (const v2f*)w2t;       // [h][128] pairs

#define PK(acc) asm volatile("v_pk_add_f32 %0, %0, %1" : "+v"(acc) : "v"(w))

#define DO_H(HB, KB)                                                      \
  do {                                                                    \
    int k_ = (int)(KB);                                                   \
    if (k_) {                                                             \
      v2f w = w2p[(size_t)(HB) * 128 + tid];                              \
      switch (k_) {                                                       \
        case 1:                                                           \
          PK(a1);  PK(a2);  PK(a3);  PK(a4);                              \
          PK(a5);  PK(a6);  PK(a7);  PK(a8);                              \
          PK(a9);  PK(a10); PK(a11); PK(a12);                             \
          PK(a13); PK(a14); PK(a15); PK(a16);                             \
          break;                                                          \
        case 2:                                                           \
          PK(a2);  PK(a4);  PK(a6);  PK(a8);                              \
          PK(a10); PK(a12); PK(a14); PK(a16);                             \
          break;                                                          \
        case 3:  PK(a3); PK(a6); PK(a9); PK(a12); PK(a15); break;         \
        case 4:  PK(a4); PK(a8); PK(a12); PK(a16); break;                 \
        case 5:  PK(a5); PK(a10); PK(a15); break;                         \
        case 6:  PK(a6); PK(a12); break;                                  \
        case 7:  PK(a7); PK(a14); break;                                  \
        case 8:  PK(a8); PK(a16); break;                                  \
        case 9:  PK(a9); break;                                           \
        case 10: PK(a10); break;                                          \
        case 11: PK(a11); break;                                          \
        case 12: PK(a12); break;                                          \
        case 13: PK(a13); break;                                          \
        case 14: PK(a14); break;                                          \
        case 15: PK(a15); break;                                          \
        default: PK(a16); break;  /* k == 16 */                           \
      }                                                                   \
    }                                                                     \
  } while (0)

  for (int it = 0; it < 32; ++it) {       // h ascending in groups of 16
    uint4 kw = kp[it];                    // wave-uniform address
    int hb = it * 16;
    {
      unsigned uw = __builtin_amdgcn_readfirstlane(kw.x);
      DO_H(hb + 0, uw & 255u);         DO_H(hb + 1, (uw >> 8) & 255u);
      DO_H(hb + 2, (uw >> 16) & 255u); DO_H(hb + 3, uw >> 24);
    }
    {
      unsigned uw = __builtin_amdgcn_readfirstlane(kw.y);
      DO_H(hb + 4, uw & 255u);         DO_H(hb + 5, (uw >> 8) & 255u);
      DO_H(hb + 6, (uw >> 16) & 255u); DO_H(hb + 7, uw >> 24);
    }
    {
      unsigned uw = __builtin_amdgcn_readfirstlane(kw.z);
      DO_H(hb + 8, uw & 255u);          DO_H(hb + 9, (uw >> 8) & 255u);
      DO_H(hb + 10, (uw >> 16) & 255u); DO_H(hb + 11, uw >> 24);
    }
    {
      unsigned uw = __builtin_amdgcn_readfirstlane(kw.w);
      DO_H(hb + 12, uw & 255u);         DO_H(hb + 13, (uw >> 8) & 255u);
      DO_H(hb + 14, (uw >> 16) & 255u); DO_H(hb + 15, uw >> 24);
    }
  }
#undef DO_H
#undef PK

  // mem2 simulation, exact fp32 per output: mem = (mem + c_t) + b2; spike.
  v2f b2v = *(const v2f*)(b2 + 2 * tid);
  float memx = 0.0f, ssx = 0.0f, memy = 0.0f, ssy = 0.0f;
#define STEP(AT)                                              \
  do {                                                        \
    memx = __fadd_rn(__fadd_rn(memx, (AT).x), b2v.x);         \
    if (memx > 0.5f) { ssx += 1.0f; memx = 0.0f; }            \
    memy = __fadd_rn(__fadd_rn(memy, (AT).y), b2v.y);         \
    if (memy > 0.5f) { ssy += 1.0f; memy = 0.0f; }            \
  } while (0)
  STEP(a1);  STEP(a2);  STEP(a3);  STEP(a4);
  STEP(a5);  STEP(a6);  STEP(a7);  STEP(a8);
  STEP(a9);  STEP(a10); STEP(a11); STEP(a12);
  STEP(a13); STEP(a14); STEP(a15); STEP(a16);
#undef STEP
  v2f r = {ssx * 0.0625f, ssy * 0.0625f};
  *(v2f*)(out + pos * OUTF + 2 * tid) = r;
}

// ---------------------------------------------------------------------------
extern "C" void kernel_launch(void* const* d_in, const int* in_sizes, int n_in,
                              void* d_out, int out_size, void* d_ws, size_t ws_size,
                              hipStream_t stream) {
  const float* X  = (const float*)d_in[0];   // [16,2048,512]
  const float* W1 = (const float*)d_in[1];   // [512,512]
  const float* b1 = (const float*)d_in[2];   // [512]
  const float* W2 = (const float*)d_in[3];   // [256,512]
  const float* b2 = (const float*)d_in[4];   // [256]
  float* out = (float*)d_out;                // [32768,256]

  float* w2t = (float*)d_ws;                                           // 512 KB
  unsigned char* kmap = (unsigned char*)d_ws + (size_t)HID * OUTF * 4; // 16 MB

  k_transpose<<<dim3(16, 8), 256, 0, stream>>>(W2, w2t);
  k_fc1_kmap<<<dim3(256, 4), 256, 0, stream>>>(X, W1, b1, kmap);
  k_snn_fc2<<<NPOS, 128, 0, stream>>>(kmap, w2t, b2, out);
}